// Round 9
// baseline (148.400 us; speedup 1.0000x reference)
//
#include <hip/hip_runtime.h>

// HeadlessAttention: B=2, K=512, Q=512, T=128
//
// logits[b,kk,q,u] = (Q_hat[b] @ diag(k[b,kk,:]) Wl^T)[q,u]
// swishmax over q (per b,kk,u); out = (sum_kk v[kk,u]*scale) @ Wo^T
//
// R8 resubmit (GPU acquisition timeout x2): CROSS-BLOCK OVERLAP.
// R6/R7 showed barrier *count* isn't the lever; the 1024-thr block =
// 1 block/CU means MFMA and VALU/reduce phases strictly alternate (both
// pipes <20% busy). Restructure K2 to 512 thr / 8 waves (wave = 64q x
// 32u), __launch_bounds__(512,4) -> 2 blocks/CU: block A's MFMA overlaps
// block B's softmax/reduce.
// NOTE: ~42us of dur_us is the harness's 256MiB d_ws poison fill - fixed.

using f16    = _Float16;
using f16x8  = __attribute__((ext_vector_type(8)))  f16;
using f32x16 = __attribute__((ext_vector_type(16))) float;

#define LOG2E 1.4426950408889634f

__device__ __forceinline__ float exp2b(float x) {
  return __builtin_amdgcn_exp2f(x);
}

__device__ __forceinline__ f16x8 cvt8(float4 a, float4 b) {
  f16x8 r;
  r[0]=(f16)a.x; r[1]=(f16)a.y; r[2]=(f16)a.z; r[3]=(f16)a.w;
  r[4]=(f16)b.x; r[5]=(f16)b.y; r[6]=(f16)b.z; r[7]=(f16)b.w;
  return r;
}

// ---------------- K1: q,k,v projections ----------------
__global__ __launch_bounds__(256, 2) void k1_proj(
    const float* __restrict__ q_tok, const float* __restrict__ k_tok,
    const float* __restrict__ v_tok, const float* __restrict__ Wq,
    const float* __restrict__ Wk,    const float* __restrict__ Wv,
    f16* __restrict__ qh, float* __restrict__ kls, float* __restrict__ vf)
{
  const int gid    = blockIdx.x;        // 0..47
  const int tensor = gid >> 4;          // 0=q 1=k 2=v
  const int sub    = gid & 15;
  const int b      = sub >> 3;
  const int rt     = sub & 7;
  const float* X = tensor==0 ? q_tok : (tensor==1 ? k_tok : v_tok);
  const float* W = tensor==0 ? Wq    : (tensor==1 ? Wk    : Wv);

  const int tid = threadIdx.x;
  const int w = tid >> 6, lane = tid & 63;
  const int l31 = lane & 31, lhi = lane >> 5;
  const int rbase = rt*64 + (w>>1)*32;
  const int cbase = (w&1)*64;

  f32x16 C0, C1;
  #pragma unroll
  for (int i=0;i<16;++i){ C0[i]=0.f; C1[i]=0.f; }

  #pragma unroll
  for (int kc=0; kc<8; ++kc) {
    const float* ap = X + (size_t)(b*512 + rbase + l31)*128 + kc*16 + 8*lhi;
    f16x8 a = cvt8(*(const float4*)ap, *(const float4*)(ap+4));
    const float* bp0 = W + (size_t)(cbase + l31)*128 + kc*16 + 8*lhi;
    f16x8 b0 = cvt8(*(const float4*)bp0, *(const float4*)(bp0+4));
    C0 = __builtin_amdgcn_mfma_f32_32x32x16_f16(a, b0, C0, 0, 0, 0);
    const float* bp1 = bp0 + 32*128;
    f16x8 b1 = cvt8(*(const float4*)bp1, *(const float4*)(bp1+4));
    C1 = __builtin_amdgcn_mfma_f32_32x32x16_f16(a, b1, C1, 0, 0, 0);
  }

  #pragma unroll
  for (int us=0; us<2; ++us) {
    #pragma unroll
    for (int r=0; r<16; ++r) {
      const int row = rbase + (r&3) + 8*(r>>2) + 4*lhi;   // verified C/D layout
      const int col = cbase + us*32 + l31;
      const float val = us ? C1[r] : C0[r];
      const size_t idx = (size_t)(b*512 + row)*128 + col;
      if (tensor==0)      qh[idx]  = (f16)val;
      else if (tensor==1) kls[idx] = val * LOG2E;   // fold log2e into k
      else                vf[idx]  = val;
    }
  }
}

// ---------------- K2: fused logits + swishmax + v-scale --------------------
// grid 256 = b(2) x uq(4: 32 u) x grp(32: 16 kk). 512 thr = 8 waves,
// wave = 64 q-rows (af in regs) x 32 u. 2 blocks/CU for phase overlap.
// Partials -> block-private contiguous 32KB region part[s][q][ul].
__global__ __launch_bounds__(512, 4) void k2_main(
    const f16* __restrict__ qh, const float* __restrict__ kls,
    const float* __restrict__ vf, const float* __restrict__ Wl,
    f16* __restrict__ part)
{
  const int gid  = blockIdx.x;          // 0..255
  const int b    = gid >> 7;
  const int uq   = (gid >> 5) & 3;
  const int grp  = gid & 31;
  const int kk0  = grp * 16;

  const int tid = threadIdx.x;
  const int w = tid >> 6, lane = tid & 63;
  const int l31 = lane & 31, lhi = lane >> 5;
  const int ubase = uq * 32;
  const int qbase = w * 64;

  __shared__ f16    Bl[2][32][136];     // [dbuf][u][t] scaled Wl, +8 pad
  __shared__ float2 red[2][8][32];      // (max, sum) per wave x u-col, dbuf

  // ---- A fragments: 64 q-rows (2 x 32), register-resident
  f16x8 af[2][8];
  {
    const f16* ab = qh + (size_t)(b*512 + qbase + l31)*128 + 8*lhi;
    #pragma unroll
    for (int qs=0; qs<2; ++qs)
      #pragma unroll
      for (int kc=0; kc<8; ++kc)
        af[qs][kc] = *(const f16x8*)(ab + qs*32*128 + kc*16);
  }

  // ---- B-build mapping: 16 threads per u-row, 8 t each
  const int bu  = tid >> 4;    // 0..31 : local u
  const int btc = tid & 15;    // 0..15 : 8-wide t chunk
  const float* wlr = Wl + (size_t)(ubase + bu)*128 + btc*8;
  const float4 wl0 = *(const float4*)(wlr);
  const float4 wl1 = *(const float4*)(wlr+4);

  const float* kbase = kls + (size_t)(b*512 + kk0)*128 + btc*8;
  const float* vbase = vf  + (size_t)(b*512 + kk0)*128 + ubase;

  f32x16 acc[2];
  #pragma unroll
  for (int i=0;i<16;++i){ acc[0][i]=0.f; acc[1][i]=0.f; }

  // ---- prologue: build Bl[0] for kk0; prefetch k-slice kk0+1
  {
    const float4 k0 = *(const float4*)(kbase);
    const float4 k1 = *(const float4*)(kbase+4);
    float4 a0 = make_float4(wl0.x*k0.x, wl0.y*k0.y, wl0.z*k0.z, wl0.w*k0.w);
    float4 a1 = make_float4(wl1.x*k1.x, wl1.y*k1.y, wl1.z*k1.z, wl1.w*k1.w);
    *(f16x8*)(&Bl[0][bu][btc*8]) = cvt8(a0, a1);
  }
  float4 n0 = *(const float4*)(kbase + 128);
  float4 n1 = *(const float4*)(kbase + 132);
  __syncthreads();

  for (int i=0; i<16; ++i) {
    const int cur = i & 1;

    const float v0 = vbase[i*128 + l31];

    // build next B-tile (overlaps MFMA in the wave schedule)
    if (i < 15) {
      float4 a0 = make_float4(wl0.x*n0.x, wl0.y*n0.y, wl0.z*n0.z, wl0.w*n0.w);
      float4 a1 = make_float4(wl1.x*n1.x, wl1.y*n1.y, wl1.z*n1.z, wl1.w*n1.w);
      *(f16x8*)(&Bl[cur^1][bu][btc*8]) = cvt8(a0, a1);
      if (i < 14) {
        const float* kp = kbase + (i+2)*128;
        n0 = *(const float4*)(kp);
        n1 = *(const float4*)(kp+4);
      }
    }

    // MFMA: C[qs] = A(64x128) @ B(128x32)
    f32x16 C[2];
    #pragma unroll
    for (int j=0;j<16;++j){ C[0][j]=0.f; C[1][j]=0.f; }
    #pragma unroll
    for (int kc=0; kc<8; ++kc) {
      f16x8 bfr = *(const f16x8*)(&Bl[cur][l31][kc*16 + 8*lhi]);
      C[0] = __builtin_amdgcn_mfma_f32_32x32x16_f16(af[0][kc], bfr, C[0], 0,0,0);
      C[1] = __builtin_amdgcn_mfma_f32_32x32x16_f16(af[1][kc], bfr, C[1], 0,0,0);
    }

    // single pass: p = y*2^y, track max(y), sum|p|
    float mxa=-3.4e38f, mxb=-3.4e38f, sa=0.f, sb=0.f;
    #pragma unroll
    for (int qs=0; qs<2; ++qs)
      #pragma unroll
      for (int r=0; r<16; ++r) {
        const float y = C[qs][r];
        const float p = y * exp2b(y);
        C[qs][r] = p;
        if (r & 1) { mxb = fmaxf(mxb, y); sb += fabsf(p); }
        else       { mxa = fmaxf(mxa, y); sa += fabsf(p); }
      }
    float mx = fmaxf(mxa, mxb);
    float sm = sa + sb;
    mx = fmaxf(mx, __shfl_xor(mx, 32));
    sm += __shfl_xor(sm, 32);
    if (lane < 32) red[cur][w][lane] = make_float2(mx, sm);

    __syncthreads();   // B1: red[cur] ready; Bl[cur^1] fully written

    // hierarchical cross-wave reduce: half-lanes read 4 entries each,
    // then shfl_xor(32) merges
    float M = -3.4e38f, S = 0.f;
    #pragma unroll
    for (int j=0; j<4; ++j) {
      const float2 t = red[cur][4*lhi + j][l31];
      M = fmaxf(M, t.x); S += t.y;
    }
    M = fmaxf(M, __shfl_xor(M, 32));
    S += __shfl_xor(S, 32);

    const float su = v0 / (S + LOG2E * exp2b(M));

    #pragma unroll
    for (int qs=0; qs<2; ++qs)
      #pragma unroll
      for (int r=0; r<16; ++r)
        acc[qs][r] = fmaf(su, C[qs][r], acc[qs][r]);

    __syncthreads();   // B2: all reads of red[cur]/Bl[cur] retired
  }

  // ---- block-private contiguous partial store: part[s][q 512][ul 32] f16
  {
    const int s = (grp<<3) + (b<<2) + uq;
    f16* pbase = part + (size_t)s*16384 + l31;
    #pragma unroll
    for (int qs=0; qs<2; ++qs)
      #pragma unroll
      for (int r=0; r<16; ++r) {
        const int q = qbase + qs*32 + (r&3) + 8*(r>>2) + 4*lhi;
        pbase[q*32] = (f16)acc[qs][r];
      }
  }
}

// ---------------- K3: reduce 32 slab-groups + out = vsum @ Wo^T (fused) ----
// grid 32 = qt(16, 32 q-rows) x b(2). 256 thr = 4 waves.
__global__ __launch_bounds__(256, 2) void k3_out(
    const f16* __restrict__ part, const float* __restrict__ Wo,
    float* __restrict__ out)
{
  const int gid = blockIdx.x;     // 0..31
  const int qt = gid >> 1, b = gid & 1;
  const int rbase = qt * 32;
  const int tid = threadIdx.x;

  __shared__ f16 vt[32][136];     // reduced vsum tile, f16

  // phase 1: slab reduction. thread -> (q = tid>>3, uc = tid&7: 16-u chunk)
  {
    const int q  = tid >> 3;
    const int uc = tid & 7;
    const int uq  = uc >> 1;            // 32-u quarter -> slab sub-index
    const int ul0 = (uc & 1) * 16;      // offset within the 32-u slab row

    float s[16];
    #pragma unroll
    for (int j=0;j<16;++j) s[j]=0.f;

    const f16* pb = part + (size_t)((b<<2) + uq)*16384 + (rbase + q)*32 + ul0;
    for (int g=0; g<32; ++g) {
      const f16x8 p0 = *(const f16x8*)(pb + (size_t)g*131072);
      const f16x8 p1 = *(const f16x8*)(pb + (size_t)g*131072 + 8);
      #pragma unroll
      for (int j=0;j<8;++j) { s[j] += (float)p0[j]; s[8+j] += (float)p1[j]; }
    }
    f16x8 o0, o1;
    #pragma unroll
    for (int j=0;j<8;++j) { o0[j] = (f16)s[j]; o1[j] = (f16)s[8+j]; }
    *(f16x8*)(&vt[q][uc*16])     = o0;
    *(f16x8*)(&vt[q][uc*16 + 8]) = o1;
  }
  __syncthreads();

  // phase 2: GEMM out[rbase..+32, :] = vt @ Wo^T ; wave w -> cols w*32..+32
  const int w = tid >> 6, lane = tid & 63;
  const int l31 = lane & 31, lhi = lane >> 5;
  const int cbase = w * 32;

  f32x16 C;
  #pragma unroll
  for (int i=0;i<16;++i) C[i] = 0.f;

  #pragma unroll
  for (int kc=0; kc<8; ++kc) {
    f16x8 a = *(const f16x8*)(&vt[l31][kc*16 + 8*lhi]);
    const float* bp = Wo + (size_t)(cbase + l31)*128 + kc*16 + 8*lhi;
    f16x8 bfr = cvt8(*(const float4*)bp, *(const float4*)(bp+4));
    C = __builtin_amdgcn_mfma_f32_32x32x16_f16(a, bfr, C, 0, 0, 0);
  }

  #pragma unroll
  for (int r=0; r<16; ++r) {
    const int row = rbase + (r&3) + 8*(r>>2) + 4*lhi;
    const int col = cbase + l31;
    out[(size_t)(b*512 + row)*128 + col] = C[r];
  }
}

extern "C" void kernel_launch(void* const* d_in, const int* in_sizes, int n_in,
                              void* d_out, int out_size, void* d_ws, size_t ws_size,
                              hipStream_t stream) {
  const float* q_tok = (const float*)d_in[0];
  const float* k_tok = (const float*)d_in[1];
  const float* v_tok = (const float*)d_in[2];
  const float* Wk    = (const float*)d_in[3];
  const float* Wq    = (const float*)d_in[4];
  const float* Wv    = (const float*)d_in[5];
  const float* Wl    = (const float*)d_in[6];
  const float* Wo    = (const float*)d_in[7];

  char* ws = (char*)d_ws;
  f16*   qh   = (f16*)  (ws);              // 262144 B
  float* kls  = (float*)(ws + 262144);     // 524288 B
  float* vf   = (float*)(ws + 786432);     // 524288 B
  f16*   part = (f16*)  (ws + 1310720);    // 256 slabs * 32KB = 8388608 B

  k1_proj<<<48, 256, 0, stream>>>(q_tok, k_tok, v_tok, Wq, Wk, Wv, qh, kls, vf);
  k2_main<<<256, 512, 0, stream>>>(qh, kls, vf, Wl, part);
  k3_out<<<32, 256, 0, stream>>>(part, Wo, (float*)d_out);
}

// Round 10
// 116.682 us; speedup vs baseline: 1.2718x; 1.2718x over previous
//
#include <hip/hip_runtime.h>

// HeadlessAttention: B=2, K=512, Q=512, T=128
//
// logits[b,kk,q,u] = (Q_hat[b] @ diag(k[b,kk,:]) Wl^T)[q,u]
// swishmax over q (per b,kk,u); out = (sum_kk v[kk,u]*scale) @ Wo^T
//
// R10: revert R8/R9 (2-blk/CU at 64q/wave needs >128 VGPR -> spills,
// WRITE 38MB, K2 70us). Back to R7 structure (1024 thr, 16 waves,
// wave=32q x 32u, af hoisted, 2kk/pair-iter), with:
//  - ONE barrier per pair-iteration (B2 removed; dbuf Bl + dbuf red make
//    it safe: build of iter i+1 writes Bl[cur_i] which is only read
//    pre-B1(i); red[cur] rewrite is fenced by the next barrier)
//  - s_setprio(1) around the MFMA cluster (T5)
// NOTE: ~42us of dur_us is the harness's 256MiB d_ws poison fill - fixed.

using f16    = _Float16;
using f16x4  = __attribute__((ext_vector_type(4)))  f16;
using f16x8  = __attribute__((ext_vector_type(8)))  f16;
using f32x16 = __attribute__((ext_vector_type(16))) float;

#define LOG2E 1.4426950408889634f

__device__ __forceinline__ float exp2b(float x) {
  return __builtin_amdgcn_exp2f(x);
}

__device__ __forceinline__ f16x8 cvt8(float4 a, float4 b) {
  f16x8 r;
  r[0]=(f16)a.x; r[1]=(f16)a.y; r[2]=(f16)a.z; r[3]=(f16)a.w;
  r[4]=(f16)b.x; r[5]=(f16)b.y; r[6]=(f16)b.z; r[7]=(f16)b.w;
  return r;
}

// ---------------- K1: q,k,v projections ----------------
__global__ __launch_bounds__(256, 2) void k1_proj(
    const float* __restrict__ q_tok, const float* __restrict__ k_tok,
    const float* __restrict__ v_tok, const float* __restrict__ Wq,
    const float* __restrict__ Wk,    const float* __restrict__ Wv,
    f16* __restrict__ qh, float* __restrict__ kls, float* __restrict__ vf)
{
  const int gid    = blockIdx.x;        // 0..47
  const int tensor = gid >> 4;          // 0=q 1=k 2=v
  const int sub    = gid & 15;
  const int b      = sub >> 3;
  const int rt     = sub & 7;
  const float* X = tensor==0 ? q_tok : (tensor==1 ? k_tok : v_tok);
  const float* W = tensor==0 ? Wq    : (tensor==1 ? Wk    : Wv);

  const int tid = threadIdx.x;
  const int w = tid >> 6, lane = tid & 63;
  const int l31 = lane & 31, lhi = lane >> 5;
  const int rbase = rt*64 + (w>>1)*32;
  const int cbase = (w&1)*64;

  f32x16 C0, C1;
  #pragma unroll
  for (int i=0;i<16;++i){ C0[i]=0.f; C1[i]=0.f; }

  #pragma unroll
  for (int kc=0; kc<8; ++kc) {
    const float* ap = X + (size_t)(b*512 + rbase + l31)*128 + kc*16 + 8*lhi;
    f16x8 a = cvt8(*(const float4*)ap, *(const float4*)(ap+4));
    const float* bp0 = W + (size_t)(cbase + l31)*128 + kc*16 + 8*lhi;
    f16x8 b0 = cvt8(*(const float4*)bp0, *(const float4*)(bp0+4));
    C0 = __builtin_amdgcn_mfma_f32_32x32x16_f16(a, b0, C0, 0, 0, 0);
    const float* bp1 = bp0 + 32*128;
    f16x8 b1 = cvt8(*(const float4*)bp1, *(const float4*)(bp1+4));
    C1 = __builtin_amdgcn_mfma_f32_32x32x16_f16(a, b1, C1, 0, 0, 0);
  }

  #pragma unroll
  for (int us=0; us<2; ++us) {
    #pragma unroll
    for (int r=0; r<16; ++r) {
      const int row = rbase + (r&3) + 8*(r>>2) + 4*lhi;   // verified C/D layout
      const int col = cbase + us*32 + l31;
      const float val = us ? C1[r] : C0[r];
      const size_t idx = (size_t)(b*512 + row)*128 + col;
      if (tensor==0)      qh[idx]  = (f16)val;
      else if (tensor==1) kls[idx] = val * LOG2E;   // fold log2e into k
      else                vf[idx]  = val;
    }
  }
}

// ---------------- K2: fused logits + swishmax + v-scale --------------------
// grid 256 = b(2) x uq(4: 32 u) x grp(32: 16 kk). 1024 thr = 16 waves,
// wave = 32 q-rows (A-frags in regs) x 32 u. 2 kk per iteration,
// ONE barrier per iteration. Partials -> block-private 32KB region.
__global__ __launch_bounds__(1024, 4) void k2_main(
    const f16* __restrict__ qh, const float* __restrict__ kls,
    const float* __restrict__ vf, const float* __restrict__ Wl,
    f16* __restrict__ part)
{
  const int gid  = blockIdx.x;          // 0..255
  const int b    = gid >> 7;
  const int uq   = (gid >> 5) & 3;
  const int grp  = gid & 31;
  const int kk0  = grp * 16;

  const int tid = threadIdx.x;
  const int w = tid >> 6, lane = tid & 63;
  const int l31 = lane & 31, lhi = lane >> 5;
  const int ubase = uq * 32;
  const int qbase = w * 32;

  __shared__ f16    Bl[2][2][32][136];  // [dbuf][kk-pair][u][t]
  __shared__ float4 red[2][16][32];     // (mx0,sm0,mx1,sm1) per wave x u-col

  // ---- A fragments: 32 q-rows, register-resident for the whole kernel
  f16x8 af[8];
  {
    const f16* ab = qh + (size_t)(b*512 + qbase + l31)*128 + 8*lhi;
    #pragma unroll
    for (int kc=0; kc<8; ++kc) af[kc] = *(const f16x8*)(ab + kc*16);
  }

  // ---- B-build mapping: 32 threads per u-row, float4 of t each
  const int bu = tid >> 5;     // 0..31 : local u
  const int tc = tid & 31;     // 0..31 : 4-wide t chunk
  const float4 wl = *(const float4*)(Wl + (size_t)(ubase + bu)*128 + tc*4);

  const float* kbase = kls + (size_t)(b*512 + kk0)*128 + tc*4;
  const float* vbase = vf  + (size_t)(b*512 + kk0)*128 + ubase;

  f32x16 acc;
  #pragma unroll
  for (int i=0;i<16;++i) acc[i]=0.f;

  // ---- prologue: build both tiles of buffer 0 (kk0, kk0+1); prefetch 2,3
  {
    const float4 ka = *(const float4*)(kbase);
    const float4 kb = *(const float4*)(kbase + 128);
    f16x4 oa, ob;
    oa[0]=(f16)(wl.x*ka.x); oa[1]=(f16)(wl.y*ka.y);
    oa[2]=(f16)(wl.z*ka.z); oa[3]=(f16)(wl.w*ka.w);
    ob[0]=(f16)(wl.x*kb.x); ob[1]=(f16)(wl.y*kb.y);
    ob[2]=(f16)(wl.z*kb.z); ob[3]=(f16)(wl.w*kb.w);
    *(f16x4*)(&Bl[0][0][bu][tc*4]) = oa;
    *(f16x4*)(&Bl[0][1][bu][tc*4]) = ob;
  }
  float4 na = *(const float4*)(kbase + 256);
  float4 nb = *(const float4*)(kbase + 384);
  __syncthreads();

  for (int i=0; i<8; ++i) {            // 8 pair-iterations = 16 kk
    const int cur = i & 1;

    const float v0 = vbase[(2*i)*128   + l31];
    const float v1 = vbase[(2*i+1)*128 + l31];

    // build next buffer's 2 tiles (safe post-B1(i-1): Bl[cur^1] readers
    // finished before that barrier)
    if (i < 7) {
      f16x4 oa, ob;
      oa[0]=(f16)(wl.x*na.x); oa[1]=(f16)(wl.y*na.y);
      oa[2]=(f16)(wl.z*na.z); oa[3]=(f16)(wl.w*na.w);
      ob[0]=(f16)(wl.x*nb.x); ob[1]=(f16)(wl.y*nb.y);
      ob[2]=(f16)(wl.z*nb.z); ob[3]=(f16)(wl.w*nb.w);
      *(f16x4*)(&Bl[cur^1][0][bu][tc*4]) = oa;
      *(f16x4*)(&Bl[cur^1][1][bu][tc*4]) = ob;
      if (i < 6) {
        na = *(const float4*)(kbase + (2*i+4)*128);
        nb = *(const float4*)(kbase + (2*i+5)*128);
      }
    }

    // MFMA: C0 = A @ B(kk even), C1 = A @ B(kk odd) - independent chains
    f32x16 C0, C1;
    #pragma unroll
    for (int j=0;j<16;++j){ C0[j]=0.f; C1[j]=0.f; }
    __builtin_amdgcn_s_setprio(1);
    #pragma unroll
    for (int kc=0; kc<8; ++kc) {
      f16x8 b0 = *(const f16x8*)(&Bl[cur][0][l31][kc*16 + 8*lhi]);
      f16x8 b1 = *(const f16x8*)(&Bl[cur][1][l31][kc*16 + 8*lhi]);
      C0 = __builtin_amdgcn_mfma_f32_32x32x16_f16(af[kc], b0, C0, 0,0,0);
      C1 = __builtin_amdgcn_mfma_f32_32x32x16_f16(af[kc], b1, C1, 0,0,0);
    }
    __builtin_amdgcn_s_setprio(0);

    // single pass both kks: p = y*2^y, track max(y), sum|p|
    float mx0a=-3.4e38f, mx0b=-3.4e38f, s0a=0.f, s0b=0.f;
    float mx1a=-3.4e38f, mx1b=-3.4e38f, s1a=0.f, s1b=0.f;
    #pragma unroll
    for (int r=0; r<16; ++r) {
      const float y0 = C0[r], y1 = C1[r];
      const float p0 = y0 * exp2b(y0);
      const float p1 = y1 * exp2b(y1);
      C0[r] = p0; C1[r] = p1;
      if (r & 1) { mx0b=fmaxf(mx0b,y0); s0b+=fabsf(p0);
                   mx1b=fmaxf(mx1b,y1); s1b+=fabsf(p1); }
      else       { mx0a=fmaxf(mx0a,y0); s0a+=fabsf(p0);
                   mx1a=fmaxf(mx1a,y1); s1a+=fabsf(p1); }
    }
    float mx0 = fmaxf(mx0a,mx0b), mx1 = fmaxf(mx1a,mx1b);
    float sm0 = s0a+s0b,          sm1 = s1a+s1b;
    mx0 = fmaxf(mx0, __shfl_xor(mx0, 32));
    mx1 = fmaxf(mx1, __shfl_xor(mx1, 32));
    sm0 += __shfl_xor(sm0, 32);
    sm1 += __shfl_xor(sm1, 32);
    if (lane < 32)
      red[cur][w][lane] = make_float4(mx0, sm0, mx1, sm1);

    __syncthreads();   // the ONLY barrier: red[cur] ready; Bl[cur^1] built

    // hierarchical cross-wave reduce: half-wave reads 8 entries, then
    // shfl_xor(32) merges the two halves
    float M0=-3.4e38f, S0=0.f, M1=-3.4e38f, S1=0.f;
    #pragma unroll
    for (int j=0; j<8; ++j) {
      const float4 t = red[cur][8*lhi + j][l31];
      M0 = fmaxf(M0, t.x); S0 += t.y;
      M1 = fmaxf(M1, t.z); S1 += t.w;
    }
    M0 = fmaxf(M0, __shfl_xor(M0, 32));
    S0 += __shfl_xor(S0, 32);
    M1 = fmaxf(M1, __shfl_xor(M1, 32));
    S1 += __shfl_xor(S1, 32);

    const float su0 = v0 / (S0 + LOG2E * exp2b(M0));
    const float su1 = v1 / (S1 + LOG2E * exp2b(M1));

    #pragma unroll
    for (int r=0; r<16; ++r) {
      acc[r] = fmaf(su0, C0[r], acc[r]);
      acc[r] = fmaf(su1, C1[r], acc[r]);
    }
    // no second barrier: next iter's Bl build targets Bl[cur^1^1]=Bl[cur]?
    // no -> iter i+1 builds Bl[(i+1)&1 ^ 1] = Bl[cur], whose readers (MFMA
    // of iter i) all finished BEFORE this iteration's barrier. red[cur^1]
    // (written next iter) is disjoint from red[cur] (read above), and
    // red[cur] is only rewritten after the NEXT barrier. Safe.
  }

  // ---- block-private contiguous partial store: part[s][q 512][ul 32] f16
  {
    const int s = (grp<<3) + (b<<2) + uq;
    f16* pbase = part + (size_t)s*16384 + l31;
    #pragma unroll
    for (int r=0; r<16; ++r) {
      const int q = qbase + (r&3) + 8*(r>>2) + 4*lhi;
      pbase[q*32] = (f16)acc[r];
    }
  }
}

// ---------------- K3: reduce 32 slab-groups + out = vsum @ Wo^T (fused) ----
// grid 32 = qt(16, 32 q-rows) x b(2). 256 thr = 4 waves.
__global__ __launch_bounds__(256, 2) void k3_out(
    const f16* __restrict__ part, const float* __restrict__ Wo,
    float* __restrict__ out)
{
  const int gid = blockIdx.x;     // 0..31
  const int qt = gid >> 1, b = gid & 1;
  const int rbase = qt * 32;
  const int tid = threadIdx.x;

  __shared__ f16 vt[32][136];     // reduced vsum tile, f16

  // phase 1: slab reduction. thread -> (q = tid>>3, uc = tid&7: 16-u chunk)
  {
    const int q  = tid >> 3;
    const int uc = tid & 7;
    const int uq  = uc >> 1;            // 32-u quarter -> slab sub-index
    const int ul0 = (uc & 1) * 16;      // offset within the 32-u slab row

    float s[16];
    #pragma unroll
    for (int j=0;j<16;++j) s[j]=0.f;

    const f16* pb = part + (size_t)((b<<2) + uq)*16384 + (rbase + q)*32 + ul0;
    for (int g=0; g<32; ++g) {
      const f16x8 p0 = *(const f16x8*)(pb + (size_t)g*131072);
      const f16x8 p1 = *(const f16x8*)(pb + (size_t)g*131072 + 8);
      #pragma unroll
      for (int j=0;j<8;++j) { s[j] += (float)p0[j]; s[8+j] += (float)p1[j]; }
    }
    f16x8 o0, o1;
    #pragma unroll
    for (int j=0;j<8;++j) { o0[j] = (f16)s[j]; o1[j] = (f16)s[8+j]; }
    *(f16x8*)(&vt[q][uc*16])     = o0;
    *(f16x8*)(&vt[q][uc*16 + 8]) = o1;
  }
  __syncthreads();

  // phase 2: GEMM out[rbase..+32, :] = vt @ Wo^T ; wave w -> cols w*32..+32
  const int w = tid >> 6, lane = tid & 63;
  const int l31 = lane & 31, lhi = lane >> 5;
  const int cbase = w * 32;

  f32x16 C;
  #pragma unroll
  for (int i=0;i<16;++i) C[i] = 0.f;

  #pragma unroll
  for (int kc=0; kc<8; ++kc) {
    f16x8 a = *(const f16x8*)(&vt[l31][kc*16 + 8*lhi]);
    const float* bp = Wo + (size_t)(cbase + l31)*128 + kc*16 + 8*lhi;
    f16x8 bfr = cvt8(*(const float4*)bp, *(const float4*)(bp+4));
    C = __builtin_amdgcn_mfma_f32_32x32x16_f16(a, bfr, C, 0, 0, 0);
  }

  #pragma unroll
  for (int r=0; r<16; ++r) {
    const int row = rbase + (r&3) + 8*(r>>2) + 4*lhi;
    const int col = cbase + l31;
    out[(size_t)(b*512 + row)*128 + col] = C[r];
  }
}

extern "C" void kernel_launch(void* const* d_in, const int* in_sizes, int n_in,
                              void* d_out, int out_size, void* d_ws, size_t ws_size,
                              hipStream_t stream) {
  const float* q_tok = (const float*)d_in[0];
  const float* k_tok = (const float*)d_in[1];
  const float* v_tok = (const float*)d_in[2];
  const float* Wk    = (const float*)d_in[3];
  const float* Wq    = (const float*)d_in[4];
  const float* Wv    = (const float*)d_in[5];
  const float* Wl    = (const float*)d_in[6];
  const float* Wo    = (const float*)d_in[7];

  char* ws = (char*)d_ws;
  f16*   qh   = (f16*)  (ws);              // 262144 B
  float* kls  = (float*)(ws + 262144);     // 524288 B
  float* vf   = (float*)(ws + 786432);     // 524288 B
  f16*   part = (f16*)  (ws + 1310720);    // 256 slabs * 32KB = 8388608 B

  k1_proj<<<48, 256, 0, stream>>>(q_tok, k_tok, v_tok, Wq, Wk, Wv, qh, kls, vf);
  k2_main<<<256, 1024, 0, stream>>>(qh, kls, vf, Wl, part);
  k3_out<<<32, 256, 0, stream>>>(part, Wo, (float*)d_out);
}

// Round 11
// 114.172 us; speedup vs baseline: 1.2998x; 1.0220x over previous
//
#include <hip/hip_runtime.h>

// HeadlessAttention: B=2, K=512, Q=512, T=128
//
// logits[b,kk,q,u] = (Q_hat[b] @ diag(k[b,kk,:]) Wl^T)[q,u]
// swishmax over q (per b,kk,u); out = (sum_kk v[kk,u]*scale) @ Wo^T
//
// R11: HALVE THE LDS-B TRAFFIC. R10 (barriers 16->8 + setprio) was
// neutral -> schedule isn't the limiter. Arithmetic says the LDS pipe is:
// 16 waves x 1 MFMA per B-read = 256KB/CU per pair-iter (~2-3k cyc @ 85
// B/cyc) > VALU > MFMA. Fix: wave = 64q (2 q-subtiles) so each B-read
// feeds 2 MFMAs; 8 waves x 512 thr, __launch_bounds__(512,2) so VGPR cap
// is 256 (R9's spill was the (512,4) 128-reg cap, not the shape).
// VGPR ~200: af 64 + C 64 + acc 32 + temps. Single barrier + setprio kept.
// NOTE: ~42us of dur_us is the harness's 256MiB d_ws poison fill - fixed.

using f16    = _Float16;
using f16x8  = __attribute__((ext_vector_type(8)))  f16;
using f32x16 = __attribute__((ext_vector_type(16))) float;

#define LOG2E 1.4426950408889634f

__device__ __forceinline__ float exp2b(float x) {
  return __builtin_amdgcn_exp2f(x);
}

__device__ __forceinline__ f16x8 cvt8(float4 a, float4 b) {
  f16x8 r;
  r[0]=(f16)a.x; r[1]=(f16)a.y; r[2]=(f16)a.z; r[3]=(f16)a.w;
  r[4]=(f16)b.x; r[5]=(f16)b.y; r[6]=(f16)b.z; r[7]=(f16)b.w;
  return r;
}

// ---------------- K1: q,k,v projections ----------------
__global__ __launch_bounds__(256, 2) void k1_proj(
    const float* __restrict__ q_tok, const float* __restrict__ k_tok,
    const float* __restrict__ v_tok, const float* __restrict__ Wq,
    const float* __restrict__ Wk,    const float* __restrict__ Wv,
    f16* __restrict__ qh, float* __restrict__ kls, float* __restrict__ vf)
{
  const int gid    = blockIdx.x;        // 0..47
  const int tensor = gid >> 4;          // 0=q 1=k 2=v
  const int sub    = gid & 15;
  const int b      = sub >> 3;
  const int rt     = sub & 7;
  const float* X = tensor==0 ? q_tok : (tensor==1 ? k_tok : v_tok);
  const float* W = tensor==0 ? Wq    : (tensor==1 ? Wk    : Wv);

  const int tid = threadIdx.x;
  const int w = tid >> 6, lane = tid & 63;
  const int l31 = lane & 31, lhi = lane >> 5;
  const int rbase = rt*64 + (w>>1)*32;
  const int cbase = (w&1)*64;

  f32x16 C0, C1;
  #pragma unroll
  for (int i=0;i<16;++i){ C0[i]=0.f; C1[i]=0.f; }

  #pragma unroll
  for (int kc=0; kc<8; ++kc) {
    const float* ap = X + (size_t)(b*512 + rbase + l31)*128 + kc*16 + 8*lhi;
    f16x8 a = cvt8(*(const float4*)ap, *(const float4*)(ap+4));
    const float* bp0 = W + (size_t)(cbase + l31)*128 + kc*16 + 8*lhi;
    f16x8 b0 = cvt8(*(const float4*)bp0, *(const float4*)(bp0+4));
    C0 = __builtin_amdgcn_mfma_f32_32x32x16_f16(a, b0, C0, 0, 0, 0);
    const float* bp1 = bp0 + 32*128;
    f16x8 b1 = cvt8(*(const float4*)bp1, *(const float4*)(bp1+4));
    C1 = __builtin_amdgcn_mfma_f32_32x32x16_f16(a, b1, C1, 0, 0, 0);
  }

  #pragma unroll
  for (int us=0; us<2; ++us) {
    #pragma unroll
    for (int r=0; r<16; ++r) {
      const int row = rbase + (r&3) + 8*(r>>2) + 4*lhi;   // verified C/D layout
      const int col = cbase + us*32 + l31;
      const float val = us ? C1[r] : C0[r];
      const size_t idx = (size_t)(b*512 + row)*128 + col;
      if (tensor==0)      qh[idx]  = (f16)val;
      else if (tensor==1) kls[idx] = val * LOG2E;   // fold log2e into k
      else                vf[idx]  = val;
    }
  }
}

// ---------------- K2: fused logits + swishmax + v-scale --------------------
// grid 256 = b(2) x uq(4: 32 u) x grp(32: 16 kk). 512 thr = 8 waves,
// wave = 64 q (2x32 subtiles, af hoisted: each B-read feeds 2 MFMAs) x
// 32 u. 2 kk per iteration, ONE barrier per iteration, (512,2) reg cap.
__global__ __launch_bounds__(512, 2) void k2_main(
    const f16* __restrict__ qh, const float* __restrict__ kls,
    const float* __restrict__ vf, const float* __restrict__ Wl,
    f16* __restrict__ part)
{
  const int gid  = blockIdx.x;          // 0..255
  const int b    = gid >> 7;
  const int uq   = (gid >> 5) & 3;
  const int grp  = gid & 31;
  const int kk0  = grp * 16;

  const int tid = threadIdx.x;
  const int w = tid >> 6, lane = tid & 63;
  const int l31 = lane & 31, lhi = lane >> 5;
  const int ubase = uq * 32;
  const int qbase = w * 64;

  __shared__ f16    Bl[2][2][32][136];  // [dbuf][kk-pair][u][t]
  __shared__ float4 red[2][8][32];      // (mx0,sm0,mx1,sm1) per wave x u-col

  // ---- A fragments: 64 q-rows (2 subtiles), register-resident (64 VGPR)
  f16x8 af[2][8];
  {
    const f16* ab = qh + (size_t)(b*512 + qbase + l31)*128 + 8*lhi;
    #pragma unroll
    for (int qs=0; qs<2; ++qs)
      #pragma unroll
      for (int kc=0; kc<8; ++kc)
        af[qs][kc] = *(const f16x8*)(ab + qs*32*128 + kc*16);
  }

  // ---- B-build mapping: 16 threads per u-row, 8 t each
  const int bu  = tid >> 4;    // 0..31 : local u
  const int btc = tid & 15;    // 0..15 : 8-wide t chunk
  const float* wlr = Wl + (size_t)(ubase + bu)*128 + btc*8;
  const float4 wl0 = *(const float4*)(wlr);
  const float4 wl1 = *(const float4*)(wlr+4);

  const float* kbase = kls + (size_t)(b*512 + kk0)*128 + btc*8;
  const float* vbase = vf  + (size_t)(b*512 + kk0)*128 + ubase;

  f32x16 acc[2];
  #pragma unroll
  for (int i=0;i<16;++i){ acc[0][i]=0.f; acc[1][i]=0.f; }

  // ---- prologue: build both tiles of buffer 0 (kk0, kk0+1); prefetch 2,3
  {
    const float4 ka0 = *(const float4*)(kbase);
    const float4 ka1 = *(const float4*)(kbase+4);
    const float4 kb0 = *(const float4*)(kbase+128);
    const float4 kb1 = *(const float4*)(kbase+132);
    float4 a0 = make_float4(wl0.x*ka0.x, wl0.y*ka0.y, wl0.z*ka0.z, wl0.w*ka0.w);
    float4 a1 = make_float4(wl1.x*ka1.x, wl1.y*ka1.y, wl1.z*ka1.z, wl1.w*ka1.w);
    float4 b0 = make_float4(wl0.x*kb0.x, wl0.y*kb0.y, wl0.z*kb0.z, wl0.w*kb0.w);
    float4 b1 = make_float4(wl1.x*kb1.x, wl1.y*kb1.y, wl1.z*kb1.z, wl1.w*kb1.w);
    *(f16x8*)(&Bl[0][0][bu][btc*8]) = cvt8(a0, a1);
    *(f16x8*)(&Bl[0][1][bu][btc*8]) = cvt8(b0, b1);
  }
  float4 na0 = *(const float4*)(kbase+256);
  float4 na1 = *(const float4*)(kbase+260);
  float4 nb0 = *(const float4*)(kbase+384);
  float4 nb1 = *(const float4*)(kbase+388);
  __syncthreads();

  for (int i=0; i<8; ++i) {            // 8 pair-iterations = 16 kk
    const int cur = i & 1;

    const float v0 = vbase[(2*i)*128   + l31];
    const float v1 = vbase[(2*i+1)*128 + l31];

    // build next buffer's 2 tiles (safe: Bl[cur^1] readers finished
    // before the previous iteration's barrier)
    if (i < 7) {
      float4 a0 = make_float4(wl0.x*na0.x, wl0.y*na0.y, wl0.z*na0.z, wl0.w*na0.w);
      float4 a1 = make_float4(wl1.x*na1.x, wl1.y*na1.y, wl1.z*na1.z, wl1.w*na1.w);
      float4 b0 = make_float4(wl0.x*nb0.x, wl0.y*nb0.y, wl0.z*nb0.z, wl0.w*nb0.w);
      float4 b1 = make_float4(wl1.x*nb1.x, wl1.y*nb1.y, wl1.z*nb1.z, wl1.w*nb1.w);
      *(f16x8*)(&Bl[cur^1][0][bu][btc*8]) = cvt8(a0, a1);
      *(f16x8*)(&Bl[cur^1][1][bu][btc*8]) = cvt8(b0, b1);
      if (i < 6) {
        const float* kp = kbase + (2*i+4)*128;
        na0 = *(const float4*)(kp);     na1 = *(const float4*)(kp+4);
        nb0 = *(const float4*)(kp+128); nb1 = *(const float4*)(kp+132);
      }
    }

    // MFMA: each B-read feeds TWO MFMAs (q-subtiles 0/1) -> LDS halved
    f32x16 C00, C01, C10, C11;
    #pragma unroll
    for (int j=0;j<16;++j){ C00[j]=0.f; C01[j]=0.f; C10[j]=0.f; C11[j]=0.f; }
    __builtin_amdgcn_s_setprio(1);
    #pragma unroll
    for (int kc=0; kc<8; ++kc) {
      f16x8 b0 = *(const f16x8*)(&Bl[cur][0][l31][kc*16 + 8*lhi]);
      f16x8 b1 = *(const f16x8*)(&Bl[cur][1][l31][kc*16 + 8*lhi]);
      C00 = __builtin_amdgcn_mfma_f32_32x32x16_f16(af[0][kc], b0, C00, 0,0,0);
      C10 = __builtin_amdgcn_mfma_f32_32x32x16_f16(af[1][kc], b0, C10, 0,0,0);
      C01 = __builtin_amdgcn_mfma_f32_32x32x16_f16(af[0][kc], b1, C01, 0,0,0);
      C11 = __builtin_amdgcn_mfma_f32_32x32x16_f16(af[1][kc], b1, C11, 0,0,0);
    }
    __builtin_amdgcn_s_setprio(0);

    // single pass both kks, both q-subtiles: p=y*2^y, track max(y), sum|p|
    float mx0a=-3.4e38f, mx0b=-3.4e38f, s0a=0.f, s0b=0.f;
    float mx1a=-3.4e38f, mx1b=-3.4e38f, s1a=0.f, s1b=0.f;
    #pragma unroll
    for (int r=0; r<16; ++r) {
      const float y00 = C00[r], y01 = C01[r];
      const float y10 = C10[r], y11 = C11[r];
      const float p00 = y00 * exp2b(y00);
      const float p01 = y01 * exp2b(y01);
      const float p10 = y10 * exp2b(y10);
      const float p11 = y11 * exp2b(y11);
      C00[r] = p00; C01[r] = p01; C10[r] = p10; C11[r] = p11;
      if (r & 1) { mx0b=fmaxf(mx0b,fmaxf(y00,y10)); s0b+=fabsf(p00)+fabsf(p10);
                   mx1b=fmaxf(mx1b,fmaxf(y01,y11)); s1b+=fabsf(p01)+fabsf(p11); }
      else       { mx0a=fmaxf(mx0a,fmaxf(y00,y10)); s0a+=fabsf(p00)+fabsf(p10);
                   mx1a=fmaxf(mx1a,fmaxf(y01,y11)); s1a+=fabsf(p01)+fabsf(p11); }
    }
    float mx0 = fmaxf(mx0a,mx0b), mx1 = fmaxf(mx1a,mx1b);
    float sm0 = s0a+s0b,          sm1 = s1a+s1b;
    mx0 = fmaxf(mx0, __shfl_xor(mx0, 32));
    mx1 = fmaxf(mx1, __shfl_xor(mx1, 32));
    sm0 += __shfl_xor(sm0, 32);
    sm1 += __shfl_xor(sm1, 32);
    if (lane < 32)
      red[cur][w][lane] = make_float4(mx0, sm0, mx1, sm1);

    __syncthreads();   // the ONLY barrier: red[cur] ready; Bl[cur^1] built

    // hierarchical cross-wave reduce: half-wave reads 4 entries, then
    // shfl_xor(32) merges the two halves
    float M0=-3.4e38f, S0=0.f, M1=-3.4e38f, S1=0.f;
    #pragma unroll
    for (int j=0; j<4; ++j) {
      const float4 t = red[cur][4*lhi + j][l31];
      M0 = fmaxf(M0, t.x); S0 += t.y;
      M1 = fmaxf(M1, t.z); S1 += t.w;
    }
    M0 = fmaxf(M0, __shfl_xor(M0, 32));
    S0 += __shfl_xor(S0, 32);
    M1 = fmaxf(M1, __shfl_xor(M1, 32));
    S1 += __shfl_xor(S1, 32);

    const float su0 = v0 / (S0 + LOG2E * exp2b(M0));
    const float su1 = v1 / (S1 + LOG2E * exp2b(M1));

    #pragma unroll
    for (int r=0; r<16; ++r) {
      acc[0][r] = fmaf(su0, C00[r], acc[0][r]);
      acc[0][r] = fmaf(su1, C01[r], acc[0][r]);
      acc[1][r] = fmaf(su0, C10[r], acc[1][r]);
      acc[1][r] = fmaf(su1, C11[r], acc[1][r]);
    }
  }

  // ---- block-private contiguous partial store: part[s][q 512][ul 32] f16
  {
    const int s = (grp<<3) + (b<<2) + uq;
    f16* pbase = part + (size_t)s*16384 + l31;
    #pragma unroll
    for (int qs=0; qs<2; ++qs)
      #pragma unroll
      for (int r=0; r<16; ++r) {
        const int q = qbase + qs*32 + (r&3) + 8*(r>>2) + 4*lhi;
        pbase[q*32] = (f16)acc[qs][r];
      }
  }
}

// ---------------- K3: reduce 32 slab-groups + out = vsum @ Wo^T (fused) ----
// grid 32 = qt(16, 32 q-rows) x b(2). 256 thr = 4 waves.
__global__ __launch_bounds__(256, 2) void k3_out(
    const f16* __restrict__ part, const float* __restrict__ Wo,
    float* __restrict__ out)
{
  const int gid = blockIdx.x;     // 0..31
  const int qt = gid >> 1, b = gid & 1;
  const int rbase = qt * 32;
  const int tid = threadIdx.x;

  __shared__ f16 vt[32][136];     // reduced vsum tile, f16

  // phase 1: slab reduction. thread -> (q = tid>>3, uc = tid&7: 16-u chunk)
  {
    const int q  = tid >> 3;
    const int uc = tid & 7;
    const int uq  = uc >> 1;            // 32-u quarter -> slab sub-index
    const int ul0 = (uc & 1) * 16;      // offset within the 32-u slab row

    float s[16];
    #pragma unroll
    for (int j=0;j<16;++j) s[j]=0.f;

    const f16* pb = part + (size_t)((b<<2) + uq)*16384 + (rbase + q)*32 + ul0;
    for (int g=0; g<32; ++g) {
      const f16x8 p0 = *(const f16x8*)(pb + (size_t)g*131072);
      const f16x8 p1 = *(const f16x8*)(pb + (size_t)g*131072 + 8);
      #pragma unroll
      for (int j=0;j<8;++j) { s[j] += (float)p0[j]; s[8+j] += (float)p1[j]; }
    }
    f16x8 o0, o1;
    #pragma unroll
    for (int j=0;j<8;++j) { o0[j] = (f16)s[j]; o1[j] = (f16)s[8+j]; }
    *(f16x8*)(&vt[q][uc*16])     = o0;
    *(f16x8*)(&vt[q][uc*16 + 8]) = o1;
  }
  __syncthreads();

  // phase 2: GEMM out[rbase..+32, :] = vt @ Wo^T ; wave w -> cols w*32..+32
  const int w = tid >> 6, lane = tid & 63;
  const int l31 = lane & 31, lhi = lane >> 5;
  const int cbase = w * 32;

  f32x16 C;
  #pragma unroll
  for (int i=0;i<16;++i) C[i] = 0.f;

  #pragma unroll
  for (int kc=0; kc<8; ++kc) {
    f16x8 a = *(const f16x8*)(&vt[l31][kc*16 + 8*lhi]);
    const float* bp = Wo + (size_t)(cbase + l31)*128 + kc*16 + 8*lhi;
    f16x8 bfr = cvt8(*(const float4*)bp, *(const float4*)(bp+4));
    C = __builtin_amdgcn_mfma_f32_32x32x16_f16(a, bfr, C, 0, 0, 0);
  }

  #pragma unroll
  for (int r=0; r<16; ++r) {
    const int row = rbase + (r&3) + 8*(r>>2) + 4*lhi;
    const int col = cbase + l31;
    out[(size_t)(b*512 + row)*128 + col] = C[r];
  }
}

extern "C" void kernel_launch(void* const* d_in, const int* in_sizes, int n_in,
                              void* d_out, int out_size, void* d_ws, size_t ws_size,
                              hipStream_t stream) {
  const float* q_tok = (const float*)d_in[0];
  const float* k_tok = (const float*)d_in[1];
  const float* v_tok = (const float*)d_in[2];
  const float* Wk    = (const float*)d_in[3];
  const float* Wq    = (const float*)d_in[4];
  const float* Wv    = (const float*)d_in[5];
  const float* Wl    = (const float*)d_in[6];
  const float* Wo    = (const float*)d_in[7];

  char* ws = (char*)d_ws;
  f16*   qh   = (f16*)  (ws);              // 262144 B
  float* kls  = (float*)(ws + 262144);     // 524288 B
  float* vf   = (float*)(ws + 786432);     // 524288 B
  f16*   part = (f16*)  (ws + 1310720);    // 256 slabs * 32KB = 8388608 B

  k1_proj<<<48, 256, 0, stream>>>(q_tok, k_tok, v_tok, Wq, Wk, Wv, qh, kls, vf);
  k2_main<<<256, 512, 0, stream>>>(qh, kls, vf, Wl, part);
  k3_out<<<32, 256, 0, stream>>>(part, Wo, (float*)d_out);
}